// Round 2
// baseline (72.077 us; speedup 1.0000x reference)
//
#include <hip/hip_runtime.h>

// DCN cross stack collapsed (verified in round 1):
//   u_k = x0.w_k, e_k = d_k.w_k (d_k = sum_{j<k} b_j), c_{k+1} = c_k(1+u_k)+e_k
//   out[t] = c_4 * (x0 . Wout[:,t]) + g_t,  g_t = d_4.Wout[:,t] + bo[t]
//
// Layout: ONE LANE PER ROW. All 12 dots are lane-local (no cross-lane reduce
// in the main loop). Weight index f is wave-uniform -> s_load (SGPR operand).
// x staged coalesced global->LDS via global_load_lds (16B), double-buffered,
// counted vmcnt(8), wave-private (no barriers). LDS read conflict (row stride
// 128B) fixed by pre-swizzling the GLOBAL source quad: LDS[r][q] holds global
// quad q^(r&7); lane r reads LDS[r][c^(r&7)] -> global quad c, conflict-free.

typedef float v4f __attribute__((ext_vector_type(4)));

__global__ __launch_bounds__(64) void cross_lane_row(
    const float* __restrict__ x, const float* __restrict__ cw,
    const float* __restrict__ cb, const float* __restrict__ Wo,
    const float* __restrict__ bo, float* __restrict__ out, int B)
{
  __shared__ float lds[4096];  // 2 buffers x 64 rows x 32 floats (8 KB each)
  const int lane = threadIdx.x;        // 64-thread block = 1 wave
  const int row0 = blockIdx.x << 6;
  const int row  = row0 + lane;

  const int swz = (lane & 7) ^ ((lane >> 3) & 7);
  const float* px = x + ((size_t)(row0 + (lane >> 3)) << 9) + (swz << 2);

#define STAGE(g, b) do {                                                      \
    const float* _s = px + ((g) << 5);                                        \
    _Pragma("unroll")                                                         \
    for (int j = 0; j < 8; ++j)                                               \
      __builtin_amdgcn_global_load_lds(                                       \
          (const __attribute__((address_space(1))) float*)(_s + (j << 12)),   \
          (__attribute__((address_space(3))) float*)(lds + ((b) << 11) + (j << 8)), \
          16, 0, 0);                                                          \
  } while (0)

#define WAITV(n) do { asm volatile("s_waitcnt vmcnt(" #n ")" ::: "memory");   \
                      __builtin_amdgcn_sched_barrier(0); } while (0)
#define WAITL()  do { asm volatile("s_waitcnt lgkmcnt(0)" ::: "memory");      \
                      __builtin_amdgcn_sched_barrier(0); } while (0)

  STAGE(0, 0);
  STAGE(1, 1);

  // ---- prologue: wave-uniform constants e1,e2,e3, gg[0..7] ----------------
  float e1p = 0.f, e2p = 0.f, e3p = 0.f;
  float gp[8] = {0.f,0.f,0.f,0.f,0.f,0.f,0.f,0.f};
  {
    const int fp = lane << 3;  // this lane's 8-float slice of F=512
    v4f b0[2], b1[2], b2[2], b3[2], w1[2], w2[2], w3[2];
    #pragma unroll
    for (int h = 0; h < 2; ++h) {
      b0[h] = *(const v4f*)(cb +        fp + 4*h);
      b1[h] = *(const v4f*)(cb +  512 + fp + 4*h);
      b2[h] = *(const v4f*)(cb + 1024 + fp + 4*h);
      b3[h] = *(const v4f*)(cb + 1536 + fp + 4*h);
      w1[h] = *(const v4f*)(cw +  512 + fp + 4*h);
      w2[h] = *(const v4f*)(cw + 1024 + fp + 4*h);
      w3[h] = *(const v4f*)(cw + 1536 + fp + 4*h);
    }
    #pragma unroll
    for (int h = 0; h < 2; ++h)
      #pragma unroll
      for (int e = 0; e < 4; ++e) {
        const float d1 = b0[h][e];
        const float d2 = d1 + b1[h][e];
        const float d3 = d2 + b2[h][e];
        const float d4 = d3 + b3[h][e];
        e1p += d1 * w1[h][e];
        e2p += d2 * w2[h][e];
        e3p += d3 * w3[h][e];
        const float* wr = Wo + ((fp + 4*h + e) << 3);
        #pragma unroll
        for (int t = 0; t < 8; ++t) gp[t] += d4 * wr[t];
      }
  }
  #pragma unroll
  for (int off = 1; off < 64; off <<= 1) {
    e1p += __shfl_xor(e1p, off);
    e2p += __shfl_xor(e2p, off);
    e3p += __shfl_xor(e3p, off);
    #pragma unroll
    for (int t = 0; t < 8; ++t) gp[t] += __shfl_xor(gp[t], off);
  }
  const float e1 = e1p, e2 = e2p, e3 = e3p;
  float gg[8];
  #pragma unroll
  for (int t = 0; t < 8; ++t) gg[t] = gp[t] + bo[t];

  // ---- main loop: 16 groups of 32 floats, double-buffered -----------------
  float u0 = 0.f, u1 = 0.f, u2 = 0.f, u3 = 0.f;
  float vt[8] = {0.f,0.f,0.f,0.f,0.f,0.f,0.f,0.f};
  const int c7 = lane & 7;
  const float* lq0 = lds + (lane << 5);
  const float* lq1 = lds + 2048 + (lane << 5);

#define COMPUTE(g, lq) do {                                                   \
    _Pragma("unroll")                                                         \
    for (int c = 0; c < 8; ++c) {                                             \
      const v4f xq = *(const v4f*)((lq) + ((c ^ c7) << 2));                   \
      const int f0 = ((g) << 5) + (c << 2);                                   \
      _Pragma("unroll")                                                       \
      for (int e = 0; e < 4; ++e) {                                           \
        const float xe = xq[e];                                               \
        const int f = f0 + e;                                                 \
        u0 += xe * cw[f];                                                     \
        u1 += xe * cw[512 + f];                                               \
        u2 += xe * cw[1024 + f];                                              \
        u3 += xe * cw[1536 + f];                                              \
        const float* _wr = Wo + (f << 3);                                     \
        _Pragma("unroll")                                                     \
        for (int t = 0; t < 8; ++t) vt[t] += xe * _wr[t];                     \
      }                                                                       \
    }                                                                         \
  } while (0)

  #pragma unroll 1
  for (int g = 0; g < 14; g += 2) {
    WAITV(8);            // group g's 8 loads done (g+1 still in flight)
    COMPUTE(g, lq0);
    WAITL();             // ds_reads of buf0 fully retired before overwrite
    STAGE(g + 2, 0);
    WAITV(8);            // group g+1 done (g+2 in flight)
    COMPUTE(g + 1, lq1);
    WAITL();
    STAGE(g + 3, 1);
  }
  WAITV(8);
  COMPUTE(14, lq0);
  WAITV(0);
  COMPUTE(15, lq1);

  // ---- epilogue -----------------------------------------------------------
  const float c1 = 1.f + u0;                 // e_0 = 0
  const float c2 = fmaf(c1, u1, c1) + e1;
  const float c3 = fmaf(c2, u2, c2) + e2;
  const float c4 = fmaf(c3, u3, c3) + e3;
  v4f o0, o1;
  #pragma unroll
  for (int t = 0; t < 4; ++t) {
    o0[t] = fmaf(c4, vt[t],     gg[t]);
    o1[t] = fmaf(c4, vt[t + 4], gg[t + 4]);
  }
  if (row < B) {
    *(v4f*)(out + ((size_t)row << 3))     = o0;
    *(v4f*)(out + ((size_t)row << 3) + 4) = o1;
  }
#undef STAGE
#undef WAITV
#undef WAITL
#undef COMPUTE
}

extern "C" void kernel_launch(void* const* d_in, const int* in_sizes, int n_in,
                              void* d_out, int out_size, void* d_ws, size_t ws_size,
                              hipStream_t stream) {
  const float* x  = (const float*)d_in[0];
  const float* cw = (const float*)d_in[1];
  const float* cb = (const float*)d_in[2];
  const float* Wo = (const float*)d_in[3];
  const float* bo = (const float*)d_in[4];
  float* out = (float*)d_out;
  const int B = in_sizes[0] / 512;   // 65536
  hipLaunchKernelGGL(cross_lane_row, dim3(B >> 6), dim3(64), 0, stream,
                     x, cw, cb, Wo, bo, out, B);
}

// Round 3
// 40.564 us; speedup vs baseline: 1.7769x; 1.7769x over previous
//
#include <hip/hip_runtime.h>

// DCN cross stack, algebraically collapsed (validated in round 1):
//   u_k = x0.w_k, e_k = d_k.w_k (d_k = sum_{j<k} b_j), c_{k+1} = c_k(1+u_k)+e_k
//   out[t] = c_4 * (x0 . Wout[:,t]) + g_t,  g_t = d_4.Wout[:,t] + bo[t]
// Wave-per-row, weights resident in VGPRs, DPP wave reduction.
// Round-3 changes vs round 1: 8 consecutive rows/wave with a depth-2 register
// prefetch pipeline; lean prologue; __launch_bounds__(256,3) for 3 waves/SIMD.

typedef float v4f __attribute__((ext_vector_type(4)));

template<int CTRL>
__device__ __forceinline__ float dpp_add(float v) {
  int t = __builtin_amdgcn_update_dpp(0, __float_as_int(v), CTRL, 0xF, 0xF, true);
  return v + __int_as_float(t);
}

// Full 64-lane sum; result valid in lane 63. VALU-only (DPP), no LDS pipe.
__device__ __forceinline__ float wave_reduce(float v) {
  v = dpp_add<0x111>(v); // row_shr:1
  v = dpp_add<0x112>(v); // row_shr:2
  v = dpp_add<0x114>(v); // row_shr:4
  v = dpp_add<0x118>(v); // row_shr:8
  v = dpp_add<0x142>(v); // row_bcast:15
  v = dpp_add<0x143>(v); // row_bcast:31
  return v;
}

__global__ __launch_bounds__(256, 3) void cross_fused3(
    const float* __restrict__ x, const float* __restrict__ cw,
    const float* __restrict__ cb, const float* __restrict__ Wo,
    const float* __restrict__ bo, float* __restrict__ out, int B)
{
  const int F = 512, T = 8;
  const int lane = threadIdx.x & 63;
  const int wid  = blockIdx.x * 4 + (threadIdx.x >> 6);
  const int r0   = wid * 8;                 // 8 consecutive rows per wave
  if (r0 >= B) return;
  const int f0 = 4 * lane;                  // owned quad 1
  const int f1 = 256 + 4 * lane;            // owned quad 2

  // ---- resident weights: cross w (8 v4f) + Wout rows (16 v4f) = 96 VGPRs --
  v4f wA[4], wB[4];
  #pragma unroll
  for (int k = 0; k < 4; ++k) {
    wA[k] = *(const v4f*)(cw + k * F + f0);
    wB[k] = *(const v4f*)(cw + k * F + f1);
  }
  v4f WoA[4][2], WoB[4][2];
  #pragma unroll
  for (int e = 0; e < 4; ++e) {
    WoA[e][0] = *(const v4f*)(Wo + (f0 + e) * T);
    WoA[e][1] = *(const v4f*)(Wo + (f0 + e) * T + 4);
    WoB[e][0] = *(const v4f*)(Wo + (f1 + e) * T);
    WoB[e][1] = *(const v4f*)(Wo + (f1 + e) * T + 4);
  }

  // ---- prologue: constants e1,e2,e3, gg[0..7] (cb streamed, 2 v4f live) ---
  float e1p = 0.f, e2p = 0.f, e3p = 0.f;
  float gp[8] = {0.f,0.f,0.f,0.f,0.f,0.f,0.f,0.f};
  {
    v4f dA = *(const v4f*)(cb + f0);             // d_1 = b_0
    v4f dB = *(const v4f*)(cb + f1);
    #pragma unroll
    for (int e = 0; e < 4; ++e) { e1p += dA[e] * wA[1][e]; e1p += dB[e] * wB[1][e]; }
    { v4f t0 = *(const v4f*)(cb + F + f0), t1 = *(const v4f*)(cb + F + f1);
      dA += t0; dB += t1; }                       // d_2
    #pragma unroll
    for (int e = 0; e < 4; ++e) { e2p += dA[e] * wA[2][e]; e2p += dB[e] * wB[2][e]; }
    { v4f t0 = *(const v4f*)(cb + 2*F + f0), t1 = *(const v4f*)(cb + 2*F + f1);
      dA += t0; dB += t1; }                       // d_3
    #pragma unroll
    for (int e = 0; e < 4; ++e) { e3p += dA[e] * wA[3][e]; e3p += dB[e] * wB[3][e]; }
    { v4f t0 = *(const v4f*)(cb + 3*F + f0), t1 = *(const v4f*)(cb + 3*F + f1);
      dA += t0; dB += t1; }                       // d_4
    #pragma unroll
    for (int e = 0; e < 4; ++e) {
      #pragma unroll
      for (int t = 0; t < 4; ++t) {
        gp[t]     += dA[e] * WoA[e][0][t]; gp[t + 4] += dA[e] * WoA[e][1][t];
        gp[t]     += dB[e] * WoB[e][0][t]; gp[t + 4] += dB[e] * WoB[e][1][t];
      }
    }
  }
  const float e1 = wave_reduce(e1p);
  const float e2 = wave_reduce(e2p);
  const float e3 = wave_reduce(e3p);
  float gg[8];
  #pragma unroll
  for (int t = 0; t < 8; ++t) gg[t] = wave_reduce(gp[t]) + bo[t]; // lane 63

  // ---- main: 8 rows, depth-2 register prefetch pipeline -------------------
  const v4f* xp = (const v4f*)x + (size_t)r0 * 128 + lane;
  v4f xa[8], xb[8];
  xa[0] = xp[0];   xb[0] = xp[64];
  xa[1] = xp[128]; xb[1] = xp[192];

  #pragma unroll
  for (int i = 0; i < 8; ++i) {
    if (i < 6) {                      // issue row i+2 before computing row i
      xa[i + 2] = xp[(size_t)(i + 2) * 128];
      xb[i + 2] = xp[(size_t)(i + 2) * 128 + 64];
    }
    float u0 = 0.f, u1 = 0.f, u2 = 0.f, u3 = 0.f;
    float vt[8] = {0.f,0.f,0.f,0.f,0.f,0.f,0.f,0.f};
    #pragma unroll
    for (int e = 0; e < 4; ++e) {
      const float xe = xa[i][e];
      u0 += xe * wA[0][e]; u1 += xe * wA[1][e];
      u2 += xe * wA[2][e]; u3 += xe * wA[3][e];
      #pragma unroll
      for (int t = 0; t < 4; ++t) { vt[t] += xe * WoA[e][0][t]; vt[t + 4] += xe * WoA[e][1][t]; }
      const float ye = xb[i][e];
      u0 += ye * wB[0][e]; u1 += ye * wB[1][e];
      u2 += ye * wB[2][e]; u3 += ye * wB[3][e];
      #pragma unroll
      for (int t = 0; t < 4; ++t) { vt[t] += ye * WoB[e][0][t]; vt[t + 4] += ye * WoB[e][1][t]; }
    }
    u0 = wave_reduce(u0); u1 = wave_reduce(u1);
    u2 = wave_reduce(u2); u3 = wave_reduce(u3);
    #pragma unroll
    for (int t = 0; t < 8; ++t) vt[t] = wave_reduce(vt[t]);

    const float c1 = 1.f + u0;                     // e_0 = 0
    const float c2 = fmaf(c1, u1, c1) + e1;
    const float c3 = fmaf(c2, u2, c2) + e2;
    const float c4 = fmaf(c3, u3, c3) + e3;
    if (lane == 63) {
      v4f o0, o1;
      #pragma unroll
      for (int t = 0; t < 4; ++t) {
        o0[t] = fmaf(c4, vt[t],     gg[t]);
        o1[t] = fmaf(c4, vt[t + 4], gg[t + 4]);
      }
      *(v4f*)(out + (size_t)(r0 + i) * 8)     = o0;
      *(v4f*)(out + (size_t)(r0 + i) * 8 + 4) = o1;
    }
  }
}

extern "C" void kernel_launch(void* const* d_in, const int* in_sizes, int n_in,
                              void* d_out, int out_size, void* d_ws, size_t ws_size,
                              hipStream_t stream) {
  const float* x  = (const float*)d_in[0];
  const float* cw = (const float*)d_in[1];
  const float* cb = (const float*)d_in[2];
  const float* Wo = (const float*)d_in[3];
  const float* bo = (const float*)d_in[4];
  float* out = (float*)d_out;
  const int B = in_sizes[0] / 512;   // 65536
  // 65536 rows / 8 rows-per-wave = 8192 waves = 2048 blocks x 4 waves
  hipLaunchKernelGGL(cross_fused3, dim3(2048), dim3(256), 0, stream,
                     x, cw, cb, Wo, bo, out, B);
}